// Round 7
// baseline (133.162 us; speedup 1.0000x reference)
//
#include <hip/hip_runtime.h>

// PhenoRotary3DPositionalEncoder
// x: (16, 8192, 6) fp32 in [0,1)  ->  enc: (16, 8192, 256) fp32
//
// For half-dim index k in [0,128):
//   k < 2  -> pad: (1, 1)
//   k >= 2 -> j=k-2, coord=j/21, f=j%21
//             a = x[pos*6+coord] * 20*pi * 10000^(-f/21)
//             enc[2k]   = cos(a)+sin(a) = sqrt2 * sin(a + pi/4)
//             enc[2k+1] = cos(a)-sin(a) = sqrt2 * cos(a + pi/4)
// In revolutions: r = fract(x * s_rev + 1/8), s_rev = 10 * 10000^(-f/21);
// pad (k<2) falls out with s_rev=0, coordoff=0: r=1/8 -> both outputs 1.
//
// Per-k (s_rev, coord byte offset) table built once per block in LDS.
// Each thread produces FOUR output float4s (quads u, u+16, u+32, u+48 of one
// position; 16 threads/position): amortizes index math + base addresses over
// 4 stores, which become offset:256/512/768 immediates. Grid exact
// (131072 pos * 16 threads = 8192 * 256) -> no bounds check.
// Plain (cacheable) stores: d_out (134 MB) fits in 256 MB Infinity Cache.

#define LOG2_10000_OVER_21 0.6327482085499738f
#define SQRT2              1.4142135623730951f

typedef float v4f __attribute__((ext_vector_type(4)));

__global__ __launch_bounds__(256) void pheno_rotary_pe_kernel(
        const float* __restrict__ x,
        v4f* __restrict__ out) {
    __shared__ float2 tbl[128];   // {s_rev, coord*4 as int bits}

    int tid = threadIdx.x;
    if (tid < 128) {
        float s = 0.0f;
        int   c4 = 0;
        if (tid >= 2) {
            int j = tid - 2;
            int c = j / 21;                 // magic-mul at -O3
            int f = j - 21 * c;
            c4 = c * 4;                     // byte offset into x row
            s = 10.0f * __builtin_amdgcn_exp2f(-LOG2_10000_OVER_21 * (float)f);
        }
        tbl[tid] = make_float2(s, __int_as_float(c4));
    }
    __syncthreads();

    int idx = blockIdx.x * 256 + tid;
    int u   = idx & 15;           // quad slot 0..15 (others: +16,+32,+48)
    int pos = idx >> 4;

    // quad u covers half-dims 2u,2u+1: table entry {s0, off0, s1, off1}
    const v4f* t4 = (const v4f*)tbl;
    v4f e0 = t4[u];
    v4f e1 = t4[u + 16];
    v4f e2 = t4[u + 32];
    v4f e3 = t4[u + 48];

    const char* xb = (const char*)x + pos * 24;   // 6 floats per position
    float x00 = *(const float*)(xb + __float_as_int(e0.y));
    float x01 = *(const float*)(xb + __float_as_int(e0.w));
    float x10 = *(const float*)(xb + __float_as_int(e1.y));
    float x11 = *(const float*)(xb + __float_as_int(e1.w));
    float x20 = *(const float*)(xb + __float_as_int(e2.y));
    float x21 = *(const float*)(xb + __float_as_int(e2.w));
    float x30 = *(const float*)(xb + __float_as_int(e3.y));
    float x31 = *(const float*)(xb + __float_as_int(e3.w));

    float r00 = __builtin_amdgcn_fractf(fmaf(x00, e0.x, 0.125f));
    float r01 = __builtin_amdgcn_fractf(fmaf(x01, e0.z, 0.125f));
    float r10 = __builtin_amdgcn_fractf(fmaf(x10, e1.x, 0.125f));
    float r11 = __builtin_amdgcn_fractf(fmaf(x11, e1.z, 0.125f));
    float r20 = __builtin_amdgcn_fractf(fmaf(x20, e2.x, 0.125f));
    float r21 = __builtin_amdgcn_fractf(fmaf(x21, e2.z, 0.125f));
    float r30 = __builtin_amdgcn_fractf(fmaf(x30, e3.x, 0.125f));
    float r31 = __builtin_amdgcn_fractf(fmaf(x31, e3.z, 0.125f));

    v4f o0, o1, o2, o3;
    o0.x = SQRT2 * __builtin_amdgcn_sinf(r00);
    o0.y = SQRT2 * __builtin_amdgcn_cosf(r00);
    o0.z = SQRT2 * __builtin_amdgcn_sinf(r01);
    o0.w = SQRT2 * __builtin_amdgcn_cosf(r01);
    o1.x = SQRT2 * __builtin_amdgcn_sinf(r10);
    o1.y = SQRT2 * __builtin_amdgcn_cosf(r10);
    o1.z = SQRT2 * __builtin_amdgcn_sinf(r11);
    o1.w = SQRT2 * __builtin_amdgcn_cosf(r11);
    o2.x = SQRT2 * __builtin_amdgcn_sinf(r20);
    o2.y = SQRT2 * __builtin_amdgcn_cosf(r20);
    o2.z = SQRT2 * __builtin_amdgcn_sinf(r21);
    o2.w = SQRT2 * __builtin_amdgcn_cosf(r21);
    o3.x = SQRT2 * __builtin_amdgcn_sinf(r30);
    o3.y = SQRT2 * __builtin_amdgcn_cosf(r30);
    o3.z = SQRT2 * __builtin_amdgcn_sinf(r31);
    o3.w = SQRT2 * __builtin_amdgcn_cosf(r31);

    v4f* ob = out + pos * 64 + u;
    ob[0]  = o0;
    ob[16] = o1;   // +256 B offset immediate
    ob[32] = o2;   // +512 B
    ob[48] = o3;   // +768 B
}

extern "C" void kernel_launch(void* const* d_in, const int* in_sizes, int n_in,
                              void* d_out, int out_size, void* d_ws, size_t ws_size,
                              hipStream_t stream) {
    const float* x = (const float*)d_in[0];
    v4f* out = (v4f*)d_out;

    int npos = in_sizes[0] / 6;          // 16 * 8192 = 131072
    int nthreads = npos * 16;            // four float4 each
    int block = 256;
    int grid = (nthreads + block - 1) / block;   // exact: 8192

    pheno_rotary_pe_kernel<<<grid, block, 0, stream>>>(x, out);
}